// Round 10
// baseline (405.635 us; speedup 1.0000x reference)
//
#include <hip/hip_runtime.h>
#include <hip/hip_bf16.h>
#include <stdint.h>

typedef __attribute__((ext_vector_type(8))) short short8;
typedef __attribute__((ext_vector_type(4))) float f32x4;

__device__ __forceinline__ short f2bf(float f) {
  __hip_bfloat16 h = __float2bfloat16(f);  // RNE
  union { __hip_bfloat16 h; unsigned short u; } c;
  c.h = h;
  return (short)c.u;
}
__device__ __forceinline__ float bf2f(short s) {
  union { unsigned u; float f; } x; x.u = ((unsigned)(unsigned short)s) << 16;
  return x.f;
}
__device__ __forceinline__ short8 cvt8(const float* p) {
  const float4 f0 = *(const float4*)p;
  const float4 f1 = *(const float4*)(p + 4);
  short8 r;
  r[0] = f2bf(f0.x); r[1] = f2bf(f0.y); r[2] = f2bf(f0.z); r[3] = f2bf(f0.w);
  r[4] = f2bf(f1.x); r[5] = f2bf(f1.y); r[6] = f2bf(f1.z); r[7] = f2bf(f1.w);
  return r;
}

// packed weights (bf16 in shorts), page = 512 shorts = 1KB:
//   Win : pages   0..191 : t*64 + K0*8 + nf             [3][8K0][8nf]
//   Wh  : pages 192..383 : 192 + t*64 + L*32 + ks*8+nf  [3][2L][4ks][8nf]
//   Wout: pages 384..575 : 384 + t*64 + K0*16 + nf      [3][4K0][16nf]
__global__ __launch_bounds__(256) void pack_weights(
    const float* __restrict__ Win, const float* __restrict__ Wh,
    const float* __restrict__ Wout, short* __restrict__ o) {
  int gid = blockIdx.x * 256 + threadIdx.x;
  if (gid < 12288) {
    int t = gid / 4096, r = gid % 4096;
    int ks = r / 512, r2 = r % 512, nf = r2 / 64, l = r2 % 64;
    int n = nf * 16 + (l & 15);
    int kb = ks * 32 + (l >> 4) * 8;
#pragma unroll
    for (int i = 0; i < 8; ++i)
      o[gid * 8 + i] = f2bf(Win[(t * 256 + kb + i) * 128 + n]);
  } else if (gid < 24576) {
    int h = gid - 12288;
    int tl = h / 2048, r = h % 2048;
    int ks = r / 512, nf = (r % 512) / 64, l = r % 64;
    int n = nf * 16 + (l & 15);
    int kb = ks * 32 + (l >> 4) * 8;
#pragma unroll
    for (int i = 0; i < 8; ++i)
      o[98304 + h * 8 + i] = f2bf(Wh[(tl * 128 + kb + i) * 128 + n]);
  } else {
    int oo = gid - 24576;
    int t = oo / 4096, r = oo % 4096;
    int ks = r / 1024, nf = (r % 1024) / 64, l = r % 64;
    int n = nf * 16 + (l & 15);
    int kb = ks * 32 + (l >> 4) * 8;
#pragma unroll
    for (int i = 0; i < 8; ++i)
      o[196608 + oo * 8 + i] = f2bf(Wout[(t * 128 + kb + i) * 256 + n]);
  }
}

// async-stage `rounds` x 4KB into LDS (linear, 256 threads).
__device__ __forceinline__ void stageN(const short* __restrict__ wp, char* lbuf,
                                       int pageBase, int tid, int rounds) {
  const char* g = (const char*)wp + (size_t)pageBase * 1024 + (size_t)tid * 16;
  char* l = lbuf + (tid >> 6) * 1024;  // wave-uniform base; HW adds lane*16
  for (int r = 0; r < rounds; ++r) {
    __builtin_amdgcn_global_load_lds(
        (const __attribute__((address_space(1))) void*)(g + r * 4096),
        (__attribute__((address_space(3))) void*)(l + r * 4096), 16, 0, 0);
  }
}

// ---- K0: U[row][256] = bf16(su[user[row]]) ----
__global__ __launch_bounds__(256) void k_gather_u(
    const int* __restrict__ user, const float* __restrict__ su,
    short* __restrict__ U, int nrows) {
  const int idx = blockIdx.x * 256 + threadIdx.x;
  const int row = idx >> 5, c = idx & 31;
  const int uid = user[row];
  *(short8*)(U + (size_t)row * 256 + c * 8) = cvt8(su + (size_t)uid * 256 + c * 8);
}

// ---- K1: L1 (stage Win_t once, grid-stride over 128-row tiles, 1 barrier) ----
__global__ __launch_bounds__(256, 2) void k_l1(
    const short* __restrict__ U, const float* __restrict__ bin,
    const short* __restrict__ wp, short* __restrict__ H1, int nrows) {
  __shared__ __align__(16) char sB[65536];
  const int tid = threadIdx.x, w = tid >> 6, lane = tid & 63;
  const int ar = lane & 15, g = lane >> 4;
  const int t = blockIdx.y;
  const f32x4 fz = {0.f, 0.f, 0.f, 0.f};

  stageN(wp, sB, t * 64, tid, 16);
  __syncthreads();

  const int ntile = nrows >> 7;
  for (int tile = blockIdx.x; tile < ntile; tile += gridDim.x) {
    const int rblk = tile << 7;
    f32x4 acc[8][2];
#pragma unroll
    for (int m = 0; m < 8; ++m) { acc[m][0] = fz; acc[m][1] = fz; }
#pragma unroll
    for (int K0 = 0; K0 < 8; ++K0) {
      short8 a[8];
#pragma unroll
      for (int m = 0; m < 8; ++m)
        a[m] = *(const short8*)(U + (size_t)(rblk + m * 16 + ar) * 256 + K0 * 32 + g * 8);
#pragma unroll
      for (int nfl = 0; nfl < 2; ++nfl) {
        const short8 b = *(const short8*)(sB + (K0 * 8 + w * 2 + nfl) * 1024 + lane * 16);
#pragma unroll
        for (int m = 0; m < 8; ++m)
          acc[m][nfl] = __builtin_amdgcn_mfma_f32_16x16x32_bf16(a[m], b, acc[m][nfl], 0, 0, 0);
      }
    }
#pragma unroll
    for (int m = 0; m < 8; ++m)
#pragma unroll
      for (int nfl = 0; nfl < 2; ++nfl) {
        const int col = w * 32 + nfl * 16 + ar;
        const float bv = bin[t * 128 + col];
#pragma unroll
        for (int q = 0; q < 4; ++q) {
          const int r = rblk + m * 16 + g * 4 + q;
          H1[((size_t)t * nrows + r) * 128 + col] = f2bf(fmaxf(acc[m][nfl][q] + bv, 0.f));
        }
      }
  }
}

// ---- K2: L2+L3 (stage Wh_t once; wave-private H2 -> zero tile barriers) ----
__global__ __launch_bounds__(256, 2) void k_l23(
    const short* __restrict__ H1, const float* __restrict__ bh,
    const short* __restrict__ wp, short* __restrict__ H3, int nrows) {
  __shared__ __align__(16) char sB[65536];
  __shared__ __align__(16) char H2[16384];  // 4 waves x 16 rows x 256B
  const int tid = threadIdx.x, w = tid >> 6, lane = tid & 63;
  const int ar = lane & 15, g = lane >> 4;
  const int t = blockIdx.y;
  const int swzA = (ar & 7) << 4;
  const f32x4 fz = {0.f, 0.f, 0.f, 0.f};

  stageN(wp, sB, 192 + t * 64, tid, 16);
  __syncthreads();

  char* const h2 = H2 + w * 4096;
  const int ntile = nrows >> 6;
  for (int tile = blockIdx.x; tile < ntile; tile += gridDim.x) {
    const int base = tile * 64 + w * 16;
    // L2: A from H1 (global, 16 rows), out -> wave-private H2
    f32x4 acc[8];
#pragma unroll
    for (int nf = 0; nf < 8; ++nf) acc[nf] = fz;
#pragma unroll
    for (int ks = 0; ks < 4; ++ks) {
      const short8 a = *(const short8*)(H1 + ((size_t)t * nrows + base + ar) * 128 + ks * 32 + g * 8);
#pragma unroll
      for (int nf = 0; nf < 8; ++nf) {
        const short8 b = *(const short8*)(sB + (ks * 8 + nf) * 1024 + lane * 16);
        acc[nf] = __builtin_amdgcn_mfma_f32_16x16x32_bf16(a, b, acc[nf], 0, 0, 0);
      }
    }
#pragma unroll
    for (int nf = 0; nf < 8; ++nf) {
      const int col = nf * 16 + ar;
      const float bv = bh[(t * 2) * 128 + col];
#pragma unroll
      for (int q = 0; q < 4; ++q) {
        const int r = g * 4 + q;
        *(short*)(h2 + r * 256 + ((col * 2) ^ ((r & 7) << 4))) =
            f2bf(fmaxf(acc[nf][q] + bv, 0.f));
      }
    }
    // L3: A from wave-private H2, out -> H3 (global)
#pragma unroll
    for (int nf = 0; nf < 8; ++nf) acc[nf] = fz;
#pragma unroll
    for (int ks = 0; ks < 4; ++ks) {
      const short8 a = *(const short8*)(h2 + ar * 256 + ((ks * 64 + g * 16) ^ swzA));
#pragma unroll
      for (int nf = 0; nf < 8; ++nf) {
        const short8 b = *(const short8*)(sB + (32 + ks * 8 + nf) * 1024 + lane * 16);
        acc[nf] = __builtin_amdgcn_mfma_f32_16x16x32_bf16(a, b, acc[nf], 0, 0, 0);
      }
    }
#pragma unroll
    for (int nf = 0; nf < 8; ++nf) {
      const int col = nf * 16 + ar;
      const float bv = bh[(t * 2 + 1) * 128 + col];
#pragma unroll
      for (int q = 0; q < 4; ++q) {
        const int r = base + g * 4 + q;
        H3[((size_t)t * nrows + r) * 128 + col] = f2bf(fmaxf(acc[nf][q] + bv, 0.f));
      }
    }
  }
}

// ---- K3: L4 (stage Wout_t once; x = bf16(acc+bout) -> global) ----
__global__ __launch_bounds__(256, 2) void k_l4(
    const short* __restrict__ H3, const float* __restrict__ bout,
    const short* __restrict__ wp, short* __restrict__ X, int nrows) {
  __shared__ __align__(16) char sB[65536];
  const int tid = threadIdx.x, w = tid >> 6, lane = tid & 63;
  const int ar = lane & 15, g = lane >> 4;
  const int t = blockIdx.y;
  const f32x4 fz = {0.f, 0.f, 0.f, 0.f};

  stageN(wp, sB, 384 + t * 64, tid, 16);
  __syncthreads();

  float bo[16];
#pragma unroll
  for (int nf = 0; nf < 16; ++nf) bo[nf] = bout[t * 256 + nf * 16 + ar];

  const int ntile = nrows >> 6;
  for (int tile = blockIdx.x; tile < ntile; tile += gridDim.x) {
    const int base = tile * 64 + w * 16;
    short8 a4[4];
#pragma unroll
    for (int K0 = 0; K0 < 4; ++K0)
      a4[K0] = *(const short8*)(H3 + ((size_t)t * nrows + base + ar) * 128 + K0 * 32 + g * 8);
    f32x4 acc[16];
#pragma unroll
    for (int nf = 0; nf < 16; ++nf) acc[nf] = fz;
#pragma unroll
    for (int K0 = 0; K0 < 4; ++K0)
#pragma unroll
      for (int nf = 0; nf < 16; ++nf) {
        const short8 b = *(const short8*)(sB + (K0 * 16 + nf) * 1024 + lane * 16);
        acc[nf] = __builtin_amdgcn_mfma_f32_16x16x32_bf16(a4[K0], b, acc[nf], 0, 0, 0);
      }
#pragma unroll
    for (int nf = 0; nf < 16; ++nf) {
      const int col = nf * 16 + ar;
#pragma unroll
      for (int q = 0; q < 4; ++q) {
        const int r = base + g * 4 + q;
        X[((size_t)t * nrows + r) * 256 + col] = f2bf(acc[nf][q] + bo[nf]);
      }
    }
  }
}

// ---- K4: tail — 4 lanes/row, coalesced, no LDS, no barrier, no atomics ----
__global__ __launch_bounds__(256) void k_tail(
    const short* __restrict__ X, const float* __restrict__ ti,
    const int* __restrict__ user, const int* __restrict__ item,
    float* __restrict__ out, int nrows) {
  const int tid = threadIdx.x;
  const int rr = tid >> 2, qq = tid & 3;
  const int row = blockIdx.x * 64 + rr;
  const int uid = user[row], itm = item[row];
  const float* kv = ti + (size_t)uid * 256 + qq * 64;
  const float* ev = ti + (size_t)itm * 256 + qq * 64;

  float l0 = 0.f, l1 = 0.f, l2 = 0.f, s0 = 0.f, s1 = 0.f, s2 = 0.f;
#pragma unroll
  for (int i = 0; i < 8; ++i) {
    const float4 ka = *(const float4*)(kv + i * 8);
    const float4 kb = *(const float4*)(kv + i * 8 + 4);
    const float4 ea = *(const float4*)(ev + i * 8);
    const float4 eb = *(const float4*)(ev + i * 8 + 4);
#pragma unroll
    for (int t = 0; t < 3; ++t) {
      const short8 xv = *(const short8*)(X + ((size_t)t * nrows + row) * 256 + qq * 64 + i * 8);
      const float x0 = bf2f(xv[0]), x1 = bf2f(xv[1]), x2 = bf2f(xv[2]), x3 = bf2f(xv[3]);
      const float x4 = bf2f(xv[4]), x5 = bf2f(xv[5]), x6 = bf2f(xv[6]), x7 = bf2f(xv[7]);
      const float dl = x0 * ka.x + x1 * ka.y + x2 * ka.z + x3 * ka.w
                     + x4 * kb.x + x5 * kb.y + x6 * kb.z + x7 * kb.w;
      const float ds = x0 * ea.x + x1 * ea.y + x2 * ea.z + x3 * ea.w
                     + x4 * eb.x + x5 * eb.y + x6 * eb.z + x7 * eb.w;
      if (t == 0) { l0 += dl; s0 += ds; }
      else if (t == 1) { l1 += dl; s1 += ds; }
      else { l2 += dl; s2 += ds; }
    }
  }
  l0 += __shfl_xor(l0, 1); l0 += __shfl_xor(l0, 2);
  l1 += __shfl_xor(l1, 1); l1 += __shfl_xor(l1, 2);
  l2 += __shfl_xor(l2, 1); l2 += __shfl_xor(l2, 2);
  s0 += __shfl_xor(s0, 1); s0 += __shfl_xor(s0, 2);
  s1 += __shfl_xor(s1, 1); s1 += __shfl_xor(s1, 2);
  s2 += __shfl_xor(s2, 1); s2 += __shfl_xor(s2, 2);
  if (qq == 0) {
    const float mx = fmaxf(l0, fmaxf(l1, l2));
    const float e0 = __expf(l0 - mx), e1 = __expf(l1 - mx), e2 = __expf(l2 - mx);
    out[row] = (e0 * s0 + e1 * s1 + e2 * s2) / (e0 + e1 + e2);
  }
}

extern "C" void kernel_launch(void* const* d_in, const int* in_sizes, int n_in,
                              void* d_out, int out_size, void* d_ws, size_t ws_size,
                              hipStream_t stream) {
  const int* user = (const int*)d_in[0];
  const int* item = (const int*)d_in[1];
  const float* su = (const float*)d_in[2];
  const float* ti = (const float*)d_in[3];
  const float* Win = (const float*)d_in[4];
  const float* bin = (const float*)d_in[5];
  const float* Wh = (const float*)d_in[6];
  const float* bh = (const float*)d_in[7];
  const float* Wout = (const float*)d_in[8];
  const float* bout = (const float*)d_in[9];
  float* out = (float*)d_out;
  char* ws = (char*)d_ws;

  const size_t WOFF = 1179648;  // packed weights region
  short* wpk = (short*)ws;
  hipLaunchKernelGGL(pack_weights, dim3(144), dim3(256), 0, stream, Win, Wh, Wout, wpk);

  // per-row ws bytes: U 512 + H1 768 + H3 768 + X 1536 = 3584
  size_t avail = (ws_size > WOFF) ? (ws_size - WOFF) : 0;
  long rpc = (long)((avail / 3584) & ~(size_t)127);
  if (rpc > 65536) rpc = 65536;
  if (rpc < 128) rpc = 128;

  short* U = (short*)(ws + WOFF);
  short* H1 = (short*)(ws + WOFF + (size_t)rpc * 512);
  short* H3 = (short*)(ws + WOFF + (size_t)rpc * 1280);
  short* X = (short*)(ws + WOFF + (size_t)rpc * 2048);

  for (long r0 = 0; r0 < 65536; r0 += rpc) {
    const int nr = (int)((65536 - r0 < rpc) ? (65536 - r0) : rpc);
    const int g1 = (nr / 128 < 170) ? (nr / 128) : 170;
    const int g2 = (nr / 64 < 170) ? (nr / 64) : 170;
    hipLaunchKernelGGL(k_gather_u, dim3(nr / 8), dim3(256), 0, stream,
                       user + r0, su, U, nr);
    hipLaunchKernelGGL(k_l1, dim3(g1, 3), dim3(256), 0, stream, U, bin, wpk, H1, nr);
    hipLaunchKernelGGL(k_l23, dim3(g2, 3), dim3(256), 0, stream, H1, bh, wpk, H3, nr);
    hipLaunchKernelGGL(k_l4, dim3(g2, 3), dim3(256), 0, stream, H3, bout, wpk, X, nr);
    hipLaunchKernelGGL(k_tail, dim3(nr / 64), dim3(256), 0, stream,
                       X, ti, user + r0, item + r0, out + r0, nr);
  }
}